// Round 5
// baseline (400.107 us; speedup 1.0000x reference)
//
#include <hip/hip_runtime.h>
#include <hip/hip_bf16.h>

// Problem constants (B=4096, D=1024 per reference setup_inputs)
#define B_ROWS 4096
#define D_DIM  1024
#define N_ROWS 8192          // 2B
#define TEMP_INV 2.0f        // 1 / 0.5

#define NTILE 64             // 8192 / 128 tiles per dim
#define GRID_SIM (NTILE * (NTILE + 1) / 2)   // 2080 upper-triangle tiles

typedef __attribute__((ext_vector_type(8))) short  bf16x8;  // 8 bf16 = 4 VGPRs
typedef __attribute__((ext_vector_type(4))) float  f32x4;   // MFMA C/D frag

__device__ inline ushort f2bf(float f) {
    union { float f; unsigned u; } v; v.f = f;
    unsigned r = v.u + 0x7fff + ((v.u >> 16) & 1);   // RNE
    return (ushort)(r >> 16);
}

// Async global->LDS DMA, 16 B per lane. LDS dest is WAVE-UNIFORM base;
// lane i's 16 B land at base + i*16 (per-lane global addr is free-form).
__device__ inline void load_lds16(const ushort* g, ushort* l) {
    __builtin_amdgcn_global_load_lds(
        (const __attribute__((address_space(1))) unsigned int*)g,
        (__attribute__((address_space(3))) unsigned int*)l,
        16, 0, 0);
}

// ---------------------------------------------------------------------------
// Kernel 1: wave-per-row L2 normalize. Block = 4 waves = 4 row pairs.
// Writes normalized bf16 reps [8192][1024], pos[b] = z_i(b).z_j(b),
// zeroes denom[8192] and the completion counter.
// ---------------------------------------------------------------------------
__global__ __launch_bounds__(256)
void normalize_kernel(const float* __restrict__ emb_i,
                      const float* __restrict__ emb_j,
                      ushort* __restrict__ reps,
                      float* __restrict__ pos,
                      float* __restrict__ denom,
                      unsigned int* __restrict__ counter) {
    const int t    = threadIdx.x;
    const int lane = t & 63;
    const int wave = t >> 6;
    const int b    = blockIdx.x * 4 + wave;          // 0..4095

    if (blockIdx.x < N_ROWS / 256) denom[blockIdx.x * 256 + t] = 0.0f;
    if (blockIdx.x == 0 && t == 0) counter[0] = 0u;

    const float4* pi = (const float4*)(emb_i + (size_t)b * D_DIM) + lane * 4;
    const float4* pj = (const float4*)(emb_j + (size_t)b * D_DIM) + lane * 4;

    float4 vi[4], vj[4];
    float si = 0.f, sj = 0.f, sd = 0.f;
    #pragma unroll
    for (int k = 0; k < 4; k++) {
        vi[k] = pi[k]; vj[k] = pj[k];
        si += vi[k].x*vi[k].x + vi[k].y*vi[k].y + vi[k].z*vi[k].z + vi[k].w*vi[k].w;
        sj += vj[k].x*vj[k].x + vj[k].y*vj[k].y + vj[k].z*vj[k].z + vj[k].w*vj[k].w;
        sd += vi[k].x*vj[k].x + vi[k].y*vj[k].y + vi[k].z*vj[k].z + vi[k].w*vj[k].w;
    }
    #pragma unroll
    for (int off = 32; off >= 1; off >>= 1) {   // butterfly: all lanes get sums
        si += __shfl_xor(si, off);
        sj += __shfl_xor(sj, off);
        sd += __shfl_xor(sd, off);
    }
    const float inv_i = 1.0f / fmaxf(sqrtf(si), 1e-12f);
    const float inv_j = 1.0f / fmaxf(sqrtf(sj), 1e-12f);
    if (lane == 0) pos[b] = sd * inv_i * inv_j;

    ushort oi[16], oj[16];
    #pragma unroll
    for (int k = 0; k < 4; k++) {
        oi[4*k+0] = f2bf(vi[k].x * inv_i); oi[4*k+1] = f2bf(vi[k].y * inv_i);
        oi[4*k+2] = f2bf(vi[k].z * inv_i); oi[4*k+3] = f2bf(vi[k].w * inv_i);
        oj[4*k+0] = f2bf(vj[k].x * inv_j); oj[4*k+1] = f2bf(vj[k].y * inv_j);
        oj[4*k+2] = f2bf(vj[k].z * inv_j); oj[4*k+3] = f2bf(vj[k].w * inv_j);
    }
    ushort* ri = reps + (size_t)b * D_DIM + lane * 16;
    ushort* rj = reps + (size_t)(b + B_ROWS) * D_DIM + lane * 16;
    *(bf16x8*)(ri)     = *(bf16x8*)(oi);
    *(bf16x8*)(ri + 8) = *(bf16x8*)(oi + 8);
    *(bf16x8*)(rj)     = *(bf16x8*)(oj);
    *(bf16x8*)(rj + 8) = *(bf16x8*)(oj + 8);
}

// ---------------------------------------------------------------------------
// Kernel 2: symmetry-halved fused sim -> exp(s/T) -> denom accumulation.
// One 128x128 upper-triangle tile (rt <= ct) per block, grid 2080.
// Enumeration ct-major (rt ascending within ct): consecutive blocks share the
// B panel (R2-proven locality pattern). Off-diag tile: column sums to
// denom[cols] AND row sums to denom[rows] (covers mirror tile). Diag tile:
// column sums only + self-mask; its B loads simply re-read the A panel.
// Inner loop = R2's proven structure: 16x16x32 MFMA, BK=32, global_load_lds
// w16, XOR chunk swizzle (measured 0 conflicts).
// __launch_bounds__(256,2): cap occupancy target at 2 waves/EU so the
// allocator never squeezes/spills (R3: forcing 3 -> 52 regs + scratch spill,
// 2.5x slower; R4: default heuristic squeezed 112->80 with same signature).
// Last block to finish computes the scalar loss.
// ---------------------------------------------------------------------------
#define BM 128
#define BK 32

__global__ __launch_bounds__(256, 2)
void sim_denom_kernel(const ushort* __restrict__ reps,
                      float* __restrict__ denom,
                      const float* __restrict__ pos,
                      unsigned int* __restrict__ counter,
                      float* __restrict__ out) {
    // triangular decode: bid -> (ct, rt), rt <= ct, prefix(ct) = ct(ct+1)/2
    const int bid = blockIdx.x;
    int ct = (int)((__builtin_sqrtf(8.0f * (float)bid + 1.0f) - 1.0f) * 0.5f);
    while ((ct + 1) * (ct + 2) / 2 <= bid) ct++;
    while (ct * (ct + 1) / 2 > bid) ct--;
    const int rt = bid - ct * (ct + 1) / 2;
    const bool isDiag = (rt == ct);

    const int rowBase = rt * BM;
    const int colBase = ct * BM;

    const int t    = threadIdx.x;
    const int lane = t & 63;
    const int wave = t >> 6;
    const int wr   = wave >> 1;           // wave row quadrant (0/1)
    const int wc   = wave & 1;            // wave col quadrant (0/1)
    const int quad = lane >> 4;           // 0..3
    const int l15  = lane & 15;

    __shared__ ushort Asmem[BM * BK];     // 8 KB, row stride 32 bf16
    __shared__ ushort Bsmem[BM * BK];     // 8 KB
    __shared__ unsigned int done;
    __shared__ float red[4];

    // staging lane map (R2-proven): lane i loads row seg*16+(i>>2), global
    // chunk (i&3)^((i>>3)&3), landing at LDS slot (i&3) of that row.
    const int rl = lane >> 2;
    const int cg = (lane & 3) ^ ((lane >> 3) & 3);
    const int seg0 = wave * 2, seg1 = wave * 2 + 1;
    const ushort* gA0 = reps + (size_t)(rowBase + seg0 * 16 + rl) * D_DIM + cg * 8;
    const ushort* gA1 = reps + (size_t)(rowBase + seg1 * 16 + rl) * D_DIM + cg * 8;
    const ushort* gB0 = reps + (size_t)(colBase + seg0 * 16 + rl) * D_DIM + cg * 8;
    const ushort* gB1 = reps + (size_t)(colBase + seg1 * 16 + rl) * D_DIM + cg * 8;

    f32x4 acc[4][4];
    #pragma unroll
    for (int mi = 0; mi < 4; mi++)
        #pragma unroll
        for (int ni = 0; ni < 4; ni++)
            acc[mi][ni] = (f32x4){0.f, 0.f, 0.f, 0.f};

    for (int kb = 0; kb < D_DIM; kb += BK) {
        __syncthreads();   // prev iter's ds_reads done before overwrite
        load_lds16(gA0 + kb, Asmem + seg0 * 512);
        load_lds16(gA1 + kb, Asmem + seg1 * 512);
        load_lds16(gB0 + kb, Bsmem + seg0 * 512);
        load_lds16(gB1 + kb, Bsmem + seg1 * 512);
        __syncthreads();   // drains vmcnt (compiler-inserted waitcnt)

        bf16x8 af[4], bfr[4];
        #pragma unroll
        for (int mi = 0; mi < 4; mi++) {
            const int r = wr * 64 + mi * 16 + l15;
            af[mi] = *(const bf16x8*)(Asmem + r * 32 + (quad ^ ((r >> 1) & 3)) * 8);
        }
        #pragma unroll
        for (int ni = 0; ni < 4; ni++) {
            const int r = wc * 64 + ni * 16 + l15;
            bfr[ni] = *(const bf16x8*)(Bsmem + r * 32 + (quad ^ ((r >> 1) & 3)) * 8);
        }

        #pragma unroll
        for (int mi = 0; mi < 4; mi++)
            #pragma unroll
            for (int ni = 0; ni < 4; ni++)
                acc[mi][ni] = __builtin_amdgcn_mfma_f32_16x16x32_bf16(
                    af[mi], bfr[ni], acc[mi][ni], 0, 0, 0);
    }

    // Epilogue. C layout: col = lane&15, row = quad*4 + reg.
    // Row sums (mirror-tile contribution) reduced+flushed per mi to keep live
    // state small (R4 lesson: fat epilogue state -> allocator squeeze/spill).
    float csum[4] = {0.f, 0.f, 0.f, 0.f};
    #pragma unroll
    for (int mi = 0; mi < 4; mi++) {
        const int rowA = rowBase + wr * 64 + mi * 16 + quad * 4;
        float prow[4] = {0.f, 0.f, 0.f, 0.f};
        #pragma unroll
        for (int ni = 0; ni < 4; ni++) {
            const int col = colBase + wc * 64 + ni * 16 + l15;
            const f32x4 a = acc[mi][ni];
            #pragma unroll
            for (int r = 0; r < 4; r++) {
                float e = __expf(a[r] * TEMP_INV);
                if (isDiag && rowA + r == col) e = 0.0f;   // self-sim mask
                csum[ni] += e;
                prow[r]  += e;
            }
        }
        if (!isDiag) {
            #pragma unroll
            for (int r = 0; r < 4; r++) {       // reduce over the 16 cols held
                float v = prow[r];              // by lanes (quad fixed, l15 var)
                v += __shfl_xor(v, 1);
                v += __shfl_xor(v, 2);
                v += __shfl_xor(v, 4);
                v += __shfl_xor(v, 8);
                if (l15 == 0) atomicAdd(denom + rowA + r, v);
            }
        }
    }
    #pragma unroll
    for (int ni = 0; ni < 4; ni++) {            // column sums across 4 quads
        float v = csum[ni];
        v += __shfl_xor(v, 16);
        v += __shfl_xor(v, 32);
        if (quad == 0)
            atomicAdd(denom + colBase + wc * 64 + ni * 16 + l15, v);
    }

    // Completion: last block to finish computes the loss.
    __threadfence();
    __syncthreads();
    if (t == 0) done = atomicAdd(counter, 1u);
    __syncthreads();
    if (done == (unsigned)(GRID_SIM - 1)) {
        __threadfence();
        float s = 0.f;
        for (int i = t; i < N_ROWS; i += 256) {
            const float d = __hip_atomic_load(denom + i, __ATOMIC_RELAXED,
                                              __HIP_MEMORY_SCOPE_AGENT);
            s += logf(d) - pos[i & (B_ROWS - 1)] * TEMP_INV;
        }
        #pragma unroll
        for (int off = 32; off >= 1; off >>= 1) s += __shfl_xor(s, off);
        if ((t & 63) == 0) red[t >> 6] = s;
        __syncthreads();
        if (t == 0) out[0] = (red[0] + red[1] + red[2] + red[3]) / (float)N_ROWS;
    }
}

// ---------------------------------------------------------------------------
extern "C" void kernel_launch(void* const* d_in, const int* in_sizes, int n_in,
                              void* d_out, int out_size, void* d_ws, size_t ws_size,
                              hipStream_t stream) {
    const float* emb_i = (const float*)d_in[0];
    const float* emb_j = (const float*)d_in[1];

    ushort* reps  = (ushort*)d_ws;                                    // 16 MB bf16 [8192][1024]
    float*  pos   = (float*)((char*)d_ws + (size_t)N_ROWS * D_DIM * sizeof(ushort)); // 16 KB
    float*  denom = pos + B_ROWS;                                     // 32 KB
    unsigned int* counter = (unsigned int*)(denom + N_ROWS);          // 4 B
    float*  out   = (float*)d_out;

    normalize_kernel<<<B_ROWS / 4, 256, 0, stream>>>(emb_i, emb_j, reps, pos, denom, counter);
    sim_denom_kernel<<<GRID_SIM, 256, 0, stream>>>(reps, denom, pos, counter, out);
}

// Round 6
// 196.482 us; speedup vs baseline: 2.0364x; 2.0364x over previous
//
#include <hip/hip_runtime.h>
#include <hip/hip_bf16.h>

// Problem constants (B=4096, D=1024 per reference setup_inputs)
#define B_ROWS 4096
#define D_DIM  1024
#define N_ROWS 8192          // 2B
#define TEMP_INV 2.0f        // 1 / 0.5

typedef __attribute__((ext_vector_type(8))) short  bf16x8;  // 8 bf16 = 4 VGPRs
typedef __attribute__((ext_vector_type(4))) float  f32x4;   // MFMA C/D frag

__device__ inline ushort f2bf(float f) {
    union { float f; unsigned u; } v; v.f = f;
    unsigned r = v.u + 0x7fff + ((v.u >> 16) & 1);   // RNE
    return (ushort)(r >> 16);
}

// Async global->LDS DMA, 16 B per lane. LDS dest is WAVE-UNIFORM base;
// lane i's 16 B land at base + i*16 (per-lane global addr is free-form).
__device__ inline void load_lds16(const ushort* g, ushort* l) {
    __builtin_amdgcn_global_load_lds(
        (const __attribute__((address_space(1))) unsigned int*)g,
        (__attribute__((address_space(3))) unsigned int*)l,
        16, 0, 0);
}

// ---------------------------------------------------------------------------
// Kernel 1: wave-per-row L2 normalize. Block = 4 waves = 4 row pairs.
// Writes normalized bf16 reps [8192][1024], pos[b] = z_i(b).z_j(b),
// zeroes denom[8192].
// ---------------------------------------------------------------------------
__global__ __launch_bounds__(256)
void normalize_kernel(const float* __restrict__ emb_i,
                      const float* __restrict__ emb_j,
                      ushort* __restrict__ reps,
                      float* __restrict__ pos,
                      float* __restrict__ denom) {
    const int t    = threadIdx.x;
    const int lane = t & 63;
    const int wave = t >> 6;
    const int b    = blockIdx.x * 4 + wave;          // 0..4095

    if (blockIdx.x < N_ROWS / 256) denom[blockIdx.x * 256 + t] = 0.0f;

    const float4* pi = (const float4*)(emb_i + (size_t)b * D_DIM) + lane * 4;
    const float4* pj = (const float4*)(emb_j + (size_t)b * D_DIM) + lane * 4;

    float4 vi[4], vj[4];
    float si = 0.f, sj = 0.f, sd = 0.f;
    #pragma unroll
    for (int k = 0; k < 4; k++) {
        vi[k] = pi[k]; vj[k] = pj[k];
        si += vi[k].x*vi[k].x + vi[k].y*vi[k].y + vi[k].z*vi[k].z + vi[k].w*vi[k].w;
        sj += vj[k].x*vj[k].x + vj[k].y*vj[k].y + vj[k].z*vj[k].z + vj[k].w*vj[k].w;
        sd += vi[k].x*vj[k].x + vi[k].y*vj[k].y + vi[k].z*vj[k].z + vi[k].w*vj[k].w;
    }
    #pragma unroll
    for (int off = 32; off >= 1; off >>= 1) {   // butterfly: all lanes get sums
        si += __shfl_xor(si, off);
        sj += __shfl_xor(sj, off);
        sd += __shfl_xor(sd, off);
    }
    const float inv_i = 1.0f / fmaxf(sqrtf(si), 1e-12f);
    const float inv_j = 1.0f / fmaxf(sqrtf(sj), 1e-12f);
    if (lane == 0) pos[b] = sd * inv_i * inv_j;

    ushort oi[16], oj[16];
    #pragma unroll
    for (int k = 0; k < 4; k++) {
        oi[4*k+0] = f2bf(vi[k].x * inv_i); oi[4*k+1] = f2bf(vi[k].y * inv_i);
        oi[4*k+2] = f2bf(vi[k].z * inv_i); oi[4*k+3] = f2bf(vi[k].w * inv_i);
        oj[4*k+0] = f2bf(vj[k].x * inv_j); oj[4*k+1] = f2bf(vj[k].y * inv_j);
        oj[4*k+2] = f2bf(vj[k].z * inv_j); oj[4*k+3] = f2bf(vj[k].w * inv_j);
    }
    ushort* ri = reps + (size_t)b * D_DIM + lane * 16;
    ushort* rj = reps + (size_t)(b + B_ROWS) * D_DIM + lane * 16;
    *(bf16x8*)(ri)     = *(bf16x8*)(oi);
    *(bf16x8*)(ri + 8) = *(bf16x8*)(oi + 8);
    *(bf16x8*)(rj)     = *(bf16x8*)(oj);
    *(bf16x8*)(rj + 8) = *(bf16x8*)(oj + 8);
}

// ---------------------------------------------------------------------------
// Kernel 2: symmetry-halved fused sim -> exp(s/T) -> denom accumulation,
// built on R2's EXACT macro-structure (measured 991 cyc/iter, FETCH
// 542 B/iter): grid 1024, rt = bid&63, cs = bid>>6, ci loop over 4 col-tiles.
// That enumeration keeps each XCD's staging working set at ~3 MB (8 A-panels
// + shared B-panel) < 4 MB L2 — R4/R5's enumerations broke this and L2
// misses made the latency-exposed 2-barrier K-loop 2.5-3x slower/iter.
// Symmetry: process ci only when ct >= rt. Off-diag tile: column sums to
// denom[cols] + row sums to denom[rows] (covers the mirror tile). Diag tile:
// masked column sums only. No device-scope fences here (loss is a separate
// kernel) — agent fences invalidate per-XCD L2 on gfx950.
// ---------------------------------------------------------------------------
#define BM 128
#define BK 32

__global__ __launch_bounds__(256)
void sim_denom_kernel(const ushort* __restrict__ reps,
                      float* __restrict__ denom) {
    const int rt = blockIdx.x & 63;       // row tile
    const int cs = blockIdx.x >> 6;       // col-split (4 col tiles each)
    const int rowBase = rt * BM;

    const int t    = threadIdx.x;
    const int lane = t & 63;
    const int wave = t >> 6;
    const int wr   = wave >> 1;           // wave row quadrant (0/1)
    const int wc   = wave & 1;            // wave col quadrant (0/1)
    const int quad = lane >> 4;           // 0..3
    const int l15  = lane & 15;

    __shared__ ushort Asmem[BM * BK];     // 8 KB, row stride 32 bf16
    __shared__ ushort Bsmem[BM * BK];     // 8 KB

    // staging lane map (R2-proven, 0 bank conflicts): lane i loads row
    // seg*16+(i>>2), global chunk (i&3)^((i>>3)&3), lands at LDS slot (i&3).
    const int rl = lane >> 2;
    const int cg = (lane & 3) ^ ((lane >> 3) & 3);
    const int seg0 = wave * 2, seg1 = wave * 2 + 1;
    const ushort* gA0 = reps + (size_t)(rowBase + seg0 * 16 + rl) * D_DIM + cg * 8;
    const ushort* gA1 = reps + (size_t)(rowBase + seg1 * 16 + rl) * D_DIM + cg * 8;

    for (int ci = 0; ci < 4; ci++) {
        const int ct = cs * 4 + ci;
        if (ct < rt) continue;            // symmetry: upper triangle only
        const bool isDiag = (ct == rt);
        const int colBase = ct * BM;

        const ushort* gB0 = reps + (size_t)(colBase + seg0 * 16 + rl) * D_DIM + cg * 8;
        const ushort* gB1 = reps + (size_t)(colBase + seg1 * 16 + rl) * D_DIM + cg * 8;

        f32x4 acc[4][4];
        #pragma unroll
        for (int mi = 0; mi < 4; mi++)
            #pragma unroll
            for (int ni = 0; ni < 4; ni++)
                acc[mi][ni] = (f32x4){0.f, 0.f, 0.f, 0.f};

        for (int kb = 0; kb < D_DIM; kb += BK) {
            __syncthreads();   // prev iter's ds_reads done before overwrite
            load_lds16(gA0 + kb, Asmem + seg0 * 512);
            load_lds16(gA1 + kb, Asmem + seg1 * 512);
            load_lds16(gB0 + kb, Bsmem + seg0 * 512);
            load_lds16(gB1 + kb, Bsmem + seg1 * 512);
            __syncthreads();   // drains vmcnt (compiler-inserted waitcnt)

            bf16x8 af[4], bfr[4];
            #pragma unroll
            for (int mi = 0; mi < 4; mi++) {
                const int r = wr * 64 + mi * 16 + l15;
                af[mi] = *(const bf16x8*)(Asmem + r * 32 + (quad ^ ((r >> 1) & 3)) * 8);
            }
            #pragma unroll
            for (int ni = 0; ni < 4; ni++) {
                const int r = wc * 64 + ni * 16 + l15;
                bfr[ni] = *(const bf16x8*)(Bsmem + r * 32 + (quad ^ ((r >> 1) & 3)) * 8);
            }

            #pragma unroll
            for (int mi = 0; mi < 4; mi++)
                #pragma unroll
                for (int ni = 0; ni < 4; ni++)
                    acc[mi][ni] = __builtin_amdgcn_mfma_f32_16x16x32_bf16(
                        af[mi], bfr[ni], acc[mi][ni], 0, 0, 0);
        }

        // Epilogue. C layout: col = lane&15, row = quad*4 + reg.
        // Row sums flushed per-mi to keep live state small.
        float csum[4] = {0.f, 0.f, 0.f, 0.f};
        #pragma unroll
        for (int mi = 0; mi < 4; mi++) {
            const int rowA = rowBase + wr * 64 + mi * 16 + quad * 4;
            float prow[4] = {0.f, 0.f, 0.f, 0.f};
            #pragma unroll
            for (int ni = 0; ni < 4; ni++) {
                const int col = colBase + wc * 64 + ni * 16 + l15;
                const f32x4 a = acc[mi][ni];
                #pragma unroll
                for (int r = 0; r < 4; r++) {
                    float e = __expf(a[r] * TEMP_INV);
                    if (isDiag && rowA + r == col) e = 0.0f;   // self-sim mask
                    csum[ni] += e;
                    prow[r]  += e;
                }
            }
            if (!isDiag) {
                #pragma unroll
                for (int r = 0; r < 4; r++) {   // reduce over 16 cols (l15 lanes)
                    float v = prow[r];
                    v += __shfl_xor(v, 1);
                    v += __shfl_xor(v, 2);
                    v += __shfl_xor(v, 4);
                    v += __shfl_xor(v, 8);
                    if (l15 == 0) atomicAdd(denom + rowA + r, v);
                }
            }
        }
        #pragma unroll
        for (int ni = 0; ni < 4; ni++) {        // column sums across 4 quads
            float v = csum[ni];
            v += __shfl_xor(v, 16);
            v += __shfl_xor(v, 32);
            if (quad == 0)
                atomicAdd(denom + colBase + wc * 64 + ni * 16 + l15, v);
        }
    }
}

// ---------------------------------------------------------------------------
// Kernel 3: loss = mean over 2B rows of (log(denom) - pos/T). Single block.
// ---------------------------------------------------------------------------
__global__ __launch_bounds__(256)
void loss_kernel(const float* __restrict__ denom,
                 const float* __restrict__ pos,
                 float* __restrict__ out) {
    const int t = threadIdx.x;
    float s = 0.f;
    for (int i = t; i < N_ROWS; i += 256) {
        const float p = pos[i & (B_ROWS - 1)];
        s += logf(denom[i]) - p * TEMP_INV;
    }
    #pragma unroll
    for (int off = 32; off >= 1; off >>= 1) s += __shfl_xor(s, off);
    __shared__ float red[4];
    if ((t & 63) == 0) red[t >> 6] = s;
    __syncthreads();
    if (t == 0) out[0] = (red[0] + red[1] + red[2] + red[3]) / (float)N_ROWS;
}

// ---------------------------------------------------------------------------
extern "C" void kernel_launch(void* const* d_in, const int* in_sizes, int n_in,
                              void* d_out, int out_size, void* d_ws, size_t ws_size,
                              hipStream_t stream) {
    const float* emb_i = (const float*)d_in[0];
    const float* emb_j = (const float*)d_in[1];

    ushort* reps  = (ushort*)d_ws;                                    // 16 MB bf16 [8192][1024]
    float*  pos   = (float*)((char*)d_ws + (size_t)N_ROWS * D_DIM * sizeof(ushort)); // 16 KB
    float*  denom = pos + B_ROWS;                                     // 32 KB
    float*  out   = (float*)d_out;

    normalize_kernel<<<B_ROWS / 4, 256, 0, stream>>>(emb_i, emb_j, reps, pos, denom);
    sim_denom_kernel<<<64 * 16, 256, 0, stream>>>(reps, denom);
    loss_kernel<<<1, 256, 0, stream>>>(denom, pos, out);
}

// Round 7
// 178.563 us; speedup vs baseline: 2.2407x; 1.1003x over previous
//
#include <hip/hip_runtime.h>
#include <hip/hip_bf16.h>

// Problem constants (B=4096, D=1024 per reference setup_inputs)
#define B_ROWS 4096
#define D_DIM  1024
#define N_ROWS 8192          // 2B
#define TEMP_INV 2.0f        // 1 / 0.5

#define NTILE 64
#define GRID_SIM 2080        // upper-triangle tiles incl. diagonal

typedef __attribute__((ext_vector_type(8))) short  bf16x8;  // 8 bf16 = 4 VGPRs
typedef __attribute__((ext_vector_type(4))) float  f32x4;   // MFMA C/D frag

__device__ inline ushort f2bf(float f) {
    union { float f; unsigned u; } v; v.f = f;
    unsigned r = v.u + 0x7fff + ((v.u >> 16) & 1);   // RNE
    return (ushort)(r >> 16);
}

// Async global->LDS DMA, 16 B per lane. LDS dest is WAVE-UNIFORM base;
// lane i's 16 B land at base + i*16 (per-lane global addr is free-form).
__device__ inline void load_lds16(const ushort* g, ushort* l) {
    __builtin_amdgcn_global_load_lds(
        (const __attribute__((address_space(1))) unsigned int*)g,
        (__attribute__((address_space(3))) unsigned int*)l,
        16, 0, 0);
}

// ---------------------------------------------------------------------------
// Kernel 1: wave-per-row L2 normalize. Block = 4 waves = 4 row pairs.
// Writes normalized bf16 reps [8192][1024], pos[b] = z_i(b).z_j(b),
// zeroes denom[8192].
// ---------------------------------------------------------------------------
__global__ __launch_bounds__(256)
void normalize_kernel(const float* __restrict__ emb_i,
                      const float* __restrict__ emb_j,
                      ushort* __restrict__ reps,
                      float* __restrict__ pos,
                      float* __restrict__ denom) {
    const int t    = threadIdx.x;
    const int lane = t & 63;
    const int wave = t >> 6;
    const int b    = blockIdx.x * 4 + wave;          // 0..4095

    if (blockIdx.x < N_ROWS / 256) denom[blockIdx.x * 256 + t] = 0.0f;

    const float4* pi = (const float4*)(emb_i + (size_t)b * D_DIM) + lane * 4;
    const float4* pj = (const float4*)(emb_j + (size_t)b * D_DIM) + lane * 4;

    float4 vi[4], vj[4];
    float si = 0.f, sj = 0.f, sd = 0.f;
    #pragma unroll
    for (int k = 0; k < 4; k++) {
        vi[k] = pi[k]; vj[k] = pj[k];
        si += vi[k].x*vi[k].x + vi[k].y*vi[k].y + vi[k].z*vi[k].z + vi[k].w*vi[k].w;
        sj += vj[k].x*vj[k].x + vj[k].y*vj[k].y + vj[k].z*vj[k].z + vj[k].w*vj[k].w;
        sd += vi[k].x*vj[k].x + vi[k].y*vj[k].y + vi[k].z*vj[k].z + vi[k].w*vj[k].w;
    }
    #pragma unroll
    for (int off = 32; off >= 1; off >>= 1) {   // butterfly: all lanes get sums
        si += __shfl_xor(si, off);
        sj += __shfl_xor(sj, off);
        sd += __shfl_xor(sd, off);
    }
    const float inv_i = 1.0f / fmaxf(sqrtf(si), 1e-12f);
    const float inv_j = 1.0f / fmaxf(sqrtf(sj), 1e-12f);
    if (lane == 0) pos[b] = sd * inv_i * inv_j;

    ushort oi[16], oj[16];
    #pragma unroll
    for (int k = 0; k < 4; k++) {
        oi[4*k+0] = f2bf(vi[k].x * inv_i); oi[4*k+1] = f2bf(vi[k].y * inv_i);
        oi[4*k+2] = f2bf(vi[k].z * inv_i); oi[4*k+3] = f2bf(vi[k].w * inv_i);
        oj[4*k+0] = f2bf(vj[k].x * inv_j); oj[4*k+1] = f2bf(vj[k].y * inv_j);
        oj[4*k+2] = f2bf(vj[k].z * inv_j); oj[4*k+3] = f2bf(vj[k].w * inv_j);
    }
    ushort* ri = reps + (size_t)b * D_DIM + lane * 16;
    ushort* rj = reps + (size_t)(b + B_ROWS) * D_DIM + lane * 16;
    *(bf16x8*)(ri)     = *(bf16x8*)(oi);
    *(bf16x8*)(ri + 8) = *(bf16x8*)(oi + 8);
    *(bf16x8*)(rj)     = *(bf16x8*)(oj);
    *(bf16x8*)(rj + 8) = *(bf16x8*)(oj + 8);
}

// ---------------------------------------------------------------------------
// Kernel 2: symmetry-halved fused sim -> exp(s/T) -> denom accumulation.
// EXACTLY one 128x128 upper-triangle tile per block (grid 2080) — perfectly
// uniform work (R6 had 0..4 tiles/block; imbalance showed as 18.7% occupancy).
// Enumeration keeps R6's measured-good locality: tiles grouped by the same
// 4-column ct-groups (g = R6's cs), rt-fast within a group, so all 16g+10
// blocks of a group share 4 B panels (1 MB) while A panels stream with 4x
// immediate reuse. Decode: prefix P(g) = 8g^2+2g; main part i<16g+4 ->
// rt=i>>2, c=i&3; 6-entry tail covers the triangular corner.
// Inner loop: R2/R6-proven (16x16x32 MFMA, BK=32, global_load_lds w16, XOR
// chunk swizzle, 0 conflicts). No device fences (R4/R5 lesson: per-block
// agent fences storm the per-XCD L2s). launch_bounds(256,3) is safe here:
// arch VGPR 84 < 106 cap, unlike R3's 32x32 variant.
// ---------------------------------------------------------------------------
#define BM 128
#define BK 32

__global__ __launch_bounds__(256, 3)
void sim_denom_kernel(const ushort* __restrict__ reps,
                      float* __restrict__ denom) {
    // ---- tile decode: bid -> (rt, ct), rt <= ct ----
    const int bid = blockIdx.x;
    int g = (int)((__builtin_sqrtf(1.0f + 8.0f * (float)bid) - 1.0f) * 0.125f);
    while (8 * (g + 1) * (g + 1) + 2 * (g + 1) <= bid) g++;   // fix float error
    while (8 * g * g + 2 * g > bid) g--;
    const int i = bid - (8 * g * g + 2 * g);    // [0, 16g+10)
    int rt, c;
    if (i < 16 * g + 4) { rt = i >> 2; c = i & 3; }
    else {
        const int r2 = i - (16 * g + 4);        // 0..5
        // corner pairs (a,b): rt = 4g+a, c = b
        const int ra[6] = {1, 1, 1, 2, 2, 3};
        const int ca[6] = {1, 2, 3, 2, 3, 3};
        rt = 4 * g + ra[r2]; c = ca[r2];
    }
    const int ct = 4 * g + c;
    const bool isDiag = (rt == ct);
    const int rowBase = rt * BM;
    const int colBase = ct * BM;

    const int t    = threadIdx.x;
    const int lane = t & 63;
    const int wave = t >> 6;
    const int wr   = wave >> 1;           // wave row quadrant (0/1)
    const int wc   = wave & 1;            // wave col quadrant (0/1)
    const int quad = lane >> 4;           // 0..3
    const int l15  = lane & 15;

    __shared__ ushort Asmem[BM * BK];     // 8 KB, row stride 32 bf16
    __shared__ ushort Bsmem[BM * BK];     // 8 KB

    // staging lane map (R2-proven, 0 bank conflicts): lane i loads row
    // seg*16+(i>>2), global chunk (i&3)^((i>>3)&3), lands at LDS slot (i&3).
    const int rl = lane >> 2;
    const int cg = (lane & 3) ^ ((lane >> 3) & 3);
    const int seg0 = wave * 2, seg1 = wave * 2 + 1;
    const ushort* gA0 = reps + (size_t)(rowBase + seg0 * 16 + rl) * D_DIM + cg * 8;
    const ushort* gA1 = reps + (size_t)(rowBase + seg1 * 16 + rl) * D_DIM + cg * 8;
    const ushort* gB0 = reps + (size_t)(colBase + seg0 * 16 + rl) * D_DIM + cg * 8;
    const ushort* gB1 = reps + (size_t)(colBase + seg1 * 16 + rl) * D_DIM + cg * 8;

    f32x4 acc[4][4];
    #pragma unroll
    for (int mi = 0; mi < 4; mi++)
        #pragma unroll
        for (int ni = 0; ni < 4; ni++)
            acc[mi][ni] = (f32x4){0.f, 0.f, 0.f, 0.f};

    for (int kb = 0; kb < D_DIM; kb += BK) {
        __syncthreads();   // prev iter's ds_reads done before overwrite
        load_lds16(gA0 + kb, Asmem + seg0 * 512);
        load_lds16(gA1 + kb, Asmem + seg1 * 512);
        load_lds16(gB0 + kb, Bsmem + seg0 * 512);
        load_lds16(gB1 + kb, Bsmem + seg1 * 512);
        __syncthreads();   // drains vmcnt (compiler-inserted waitcnt)

        bf16x8 af[4], bfr[4];
        #pragma unroll
        for (int mi = 0; mi < 4; mi++) {
            const int r = wr * 64 + mi * 16 + l15;
            af[mi] = *(const bf16x8*)(Asmem + r * 32 + (quad ^ ((r >> 1) & 3)) * 8);
        }
        #pragma unroll
        for (int ni = 0; ni < 4; ni++) {
            const int r = wc * 64 + ni * 16 + l15;
            bfr[ni] = *(const bf16x8*)(Bsmem + r * 32 + (quad ^ ((r >> 1) & 3)) * 8);
        }

        #pragma unroll
        for (int mi = 0; mi < 4; mi++)
            #pragma unroll
            for (int ni = 0; ni < 4; ni++)
                acc[mi][ni] = __builtin_amdgcn_mfma_f32_16x16x32_bf16(
                    af[mi], bfr[ni], acc[mi][ni], 0, 0, 0);
    }

    // Epilogue. C layout: col = lane&15, row = quad*4 + reg.
    // Row sums (mirror-tile contribution) flushed per-mi to keep live state
    // small; column sums accumulated across and flushed at the end.
    float csum[4] = {0.f, 0.f, 0.f, 0.f};
    #pragma unroll
    for (int mi = 0; mi < 4; mi++) {
        const int rowA = rowBase + wr * 64 + mi * 16 + quad * 4;
        float prow[4] = {0.f, 0.f, 0.f, 0.f};
        #pragma unroll
        for (int ni = 0; ni < 4; ni++) {
            const int col = colBase + wc * 64 + ni * 16 + l15;
            const f32x4 a = acc[mi][ni];
            #pragma unroll
            for (int r = 0; r < 4; r++) {
                float e = __expf(a[r] * TEMP_INV);
                if (isDiag && rowA + r == col) e = 0.0f;   // self-sim mask
                csum[ni] += e;
                prow[r]  += e;
            }
        }
        if (!isDiag) {
            #pragma unroll
            for (int r = 0; r < 4; r++) {   // reduce over 16 cols (l15 lanes)
                float v = prow[r];
                v += __shfl_xor(v, 1);
                v += __shfl_xor(v, 2);
                v += __shfl_xor(v, 4);
                v += __shfl_xor(v, 8);
                if (l15 == 0) atomicAdd(denom + rowA + r, v);
            }
        }
    }
    #pragma unroll
    for (int ni = 0; ni < 4; ni++) {        // column sums across 4 quads
        float v = csum[ni];
        v += __shfl_xor(v, 16);
        v += __shfl_xor(v, 32);
        if (quad == 0)
            atomicAdd(denom + colBase + wc * 64 + ni * 16 + l15, v);
    }
}

// ---------------------------------------------------------------------------
// Kernel 3: loss = mean over 2B rows of (log(denom) - pos/T). Single block.
// ---------------------------------------------------------------------------
__global__ __launch_bounds__(256)
void loss_kernel(const float* __restrict__ denom,
                 const float* __restrict__ pos,
                 float* __restrict__ out) {
    const int t = threadIdx.x;
    float s = 0.f;
    for (int i = t; i < N_ROWS; i += 256) {
        const float p = pos[i & (B_ROWS - 1)];
        s += logf(denom[i]) - p * TEMP_INV;
    }
    #pragma unroll
    for (int off = 32; off >= 1; off >>= 1) s += __shfl_xor(s, off);
    __shared__ float red[4];
    if ((t & 63) == 0) red[t >> 6] = s;
    __syncthreads();
    if (t == 0) out[0] = (red[0] + red[1] + red[2] + red[3]) / (float)N_ROWS;
}

// ---------------------------------------------------------------------------
extern "C" void kernel_launch(void* const* d_in, const int* in_sizes, int n_in,
                              void* d_out, int out_size, void* d_ws, size_t ws_size,
                              hipStream_t stream) {
    const float* emb_i = (const float*)d_in[0];
    const float* emb_j = (const float*)d_in[1];

    ushort* reps  = (ushort*)d_ws;                                    // 16 MB bf16 [8192][1024]
    float*  pos   = (float*)((char*)d_ws + (size_t)N_ROWS * D_DIM * sizeof(ushort)); // 16 KB
    float*  denom = pos + B_ROWS;                                     // 32 KB
    float*  out   = (float*)d_out;

    normalize_kernel<<<B_ROWS / 4, 256, 0, stream>>>(emb_i, emb_j, reps, pos, denom);
    sim_denom_kernel<<<GRID_SIM, 256, 0, stream>>>(reps, denom);
    loss_kernel<<<1, 256, 0, stream>>>(denom, pos, out);
}

// Round 8
// 150.035 us; speedup vs baseline: 2.6668x; 1.1901x over previous
//
#include <hip/hip_runtime.h>
#include <hip/hip_bf16.h>

// Problem constants (B=4096, D=1024 per reference setup_inputs)
#define B_ROWS 4096
#define D_DIM  1024          // elements == bytes in fp8
#define N_ROWS 8192          // 2B
// values scaled by 16 before fp8 cast -> sim scaled by 256; exp arg factor:
#define EXP_SCALE 0.0078125f // TEMP_INV / 256 = 2/256
#define FP8_SCALE 16.0f

#define NTILE 64
#define GRID_SIM 2080        // upper-triangle tiles incl. diagonal

typedef __attribute__((ext_vector_type(4))) float f32x4;   // MFMA C/D frag

// Async global->LDS DMA, 16 B per lane. LDS dest is WAVE-UNIFORM base;
// lane i's 16 B land at base + i*16 (per-lane global addr is free-form).
__device__ inline void load_lds16(const unsigned char* g, unsigned char* l) {
    __builtin_amdgcn_global_load_lds(
        (const __attribute__((address_space(1))) unsigned int*)g,
        (__attribute__((address_space(3))) unsigned int*)l,
        16, 0, 0);
}

// ---------------------------------------------------------------------------
// Kernel 1: wave-per-row L2 normalize -> fp8 e4m3 reps (x16 scale), [8192]
// rows x 1024 B. pos[b] = z_i(b).z_j(b) in fp32 (exact). Zeroes denom.
// ---------------------------------------------------------------------------
__global__ __launch_bounds__(256)
void normalize_kernel(const float* __restrict__ emb_i,
                      const float* __restrict__ emb_j,
                      unsigned char* __restrict__ reps,
                      float* __restrict__ pos,
                      float* __restrict__ denom) {
    const int t    = threadIdx.x;
    const int lane = t & 63;
    const int wave = t >> 6;
    const int b    = blockIdx.x * 4 + wave;          // 0..4095

    if (blockIdx.x < N_ROWS / 256) denom[blockIdx.x * 256 + t] = 0.0f;

    const float4* pi = (const float4*)(emb_i + (size_t)b * D_DIM) + lane * 4;
    const float4* pj = (const float4*)(emb_j + (size_t)b * D_DIM) + lane * 4;

    float4 vi[4], vj[4];
    float si = 0.f, sj = 0.f, sd = 0.f;
    #pragma unroll
    for (int k = 0; k < 4; k++) {
        vi[k] = pi[k]; vj[k] = pj[k];
        si += vi[k].x*vi[k].x + vi[k].y*vi[k].y + vi[k].z*vi[k].z + vi[k].w*vi[k].w;
        sj += vj[k].x*vj[k].x + vj[k].y*vj[k].y + vj[k].z*vj[k].z + vj[k].w*vj[k].w;
        sd += vi[k].x*vj[k].x + vi[k].y*vj[k].y + vi[k].z*vj[k].z + vi[k].w*vj[k].w;
    }
    #pragma unroll
    for (int off = 32; off >= 1; off >>= 1) {   // butterfly: all lanes get sums
        si += __shfl_xor(si, off);
        sj += __shfl_xor(sj, off);
        sd += __shfl_xor(sd, off);
    }
    const float inv_i = FP8_SCALE / fmaxf(sqrtf(si), 1e-12f);
    const float inv_j = FP8_SCALE / fmaxf(sqrtf(sj), 1e-12f);
    if (lane == 0) pos[b] = sd * (inv_i * inv_j) * (1.0f / (FP8_SCALE * FP8_SCALE));

    uint4 wi, wj;
    unsigned int* wip = (unsigned int*)&wi;
    unsigned int* wjp = (unsigned int*)&wj;
    #pragma unroll
    for (int k = 0; k < 4; k++) {
        int a = __builtin_amdgcn_cvt_pk_fp8_f32(vi[k].x * inv_i, vi[k].y * inv_i, 0, false);
        wip[k] = __builtin_amdgcn_cvt_pk_fp8_f32(vi[k].z * inv_i, vi[k].w * inv_i, a, true);
        int c = __builtin_amdgcn_cvt_pk_fp8_f32(vj[k].x * inv_j, vj[k].y * inv_j, 0, false);
        wjp[k] = __builtin_amdgcn_cvt_pk_fp8_f32(vj[k].z * inv_j, vj[k].w * inv_j, c, true);
    }
    *(uint4*)(reps + (size_t)b * D_DIM + lane * 16)            = wi;
    *(uint4*)(reps + (size_t)(b + B_ROWS) * D_DIM + lane * 16) = wj;
}

// ---------------------------------------------------------------------------
// Kernel 2: symmetry-halved fused sim -> exp -> denom, fp8 e4m3 MFMA.
// One 128x128 upper-triangle tile per block (grid 2080, R7's balanced
// ct-group enumeration). BK = 64 fp8 elements (64 B rows — SAME LDS geometry
// as the proven bf16 kernel: 4x16B chunks/row, XOR chunk swizzle, staging map
// measured 0-conflict). K-iters halve (16): half the barriers, half the
// staging and LDS bytes; MFMA count unchanged (fp8 K=32 = bf16 rate).
// Fragments: ds_read_b64 (8 fp8/lane); A/B use the same lane->k map so any
// k-permutation cancels in the dot product. C/D layout is dtype-independent.
// ---------------------------------------------------------------------------
#define BM 128
#define BKB 64               // K-bytes (== elements) staged per iter

__global__ __launch_bounds__(256, 3)
void sim_denom_kernel(const unsigned char* __restrict__ reps,
                      float* __restrict__ denom) {
    // ---- tile decode: bid -> (rt, ct), rt <= ct (R7 grouped enumeration) ----
    const int bid = blockIdx.x;
    int g = (int)((__builtin_sqrtf(1.0f + 8.0f * (float)bid) - 1.0f) * 0.125f);
    while (8 * (g + 1) * (g + 1) + 2 * (g + 1) <= bid) g++;
    while (8 * g * g + 2 * g > bid) g--;
    const int i = bid - (8 * g * g + 2 * g);    // [0, 16g+10)
    int rt, c;
    if (i < 16 * g + 4) { rt = i >> 2; c = i & 3; }
    else {
        const int r2 = i - (16 * g + 4);        // 0..5
        const int ra[6] = {1, 1, 1, 2, 2, 3};
        const int ca[6] = {1, 2, 3, 2, 3, 3};
        rt = 4 * g + ra[r2]; c = ca[r2];
    }
    const int ct = 4 * g + c;
    const bool isDiag = (rt == ct);
    const int rowBase = rt * BM;
    const int colBase = ct * BM;

    const int t    = threadIdx.x;
    const int lane = t & 63;
    const int wave = t >> 6;
    const int wr   = wave >> 1;           // wave row quadrant (0/1)
    const int wc   = wave & 1;            // wave col quadrant (0/1)
    const int quad = lane >> 4;           // 0..3
    const int l15  = lane & 15;

    __shared__ unsigned char Asmem[BM * BKB];   // 8 KB, 64-B rows
    __shared__ unsigned char Bsmem[BM * BKB];   // 8 KB

    // staging lane map (R2-proven geometry): lane i -> row seg*16+(i>>2),
    // LDS slot i&3, global 16-B chunk (i&3)^((i>>3)&3).
    const int rl = lane >> 2;
    const int cg = (lane & 3) ^ ((lane >> 3) & 3);
    const int seg0 = wave * 2, seg1 = wave * 2 + 1;
    const unsigned char* gA0 = reps + (size_t)(rowBase + seg0 * 16 + rl) * D_DIM + cg * 16;
    const unsigned char* gA1 = reps + (size_t)(rowBase + seg1 * 16 + rl) * D_DIM + cg * 16;
    const unsigned char* gB0 = reps + (size_t)(colBase + seg0 * 16 + rl) * D_DIM + cg * 16;
    const unsigned char* gB1 = reps + (size_t)(colBase + seg1 * 16 + rl) * D_DIM + cg * 16;

    // fragment read offsets (bytes): frag (row r, kstep ks, quad q) = global
    // bytes [ks*32 + q*8, +8) of row r -> chunk c = ks*2 + (q>>1), slot =
    // c ^ ((r>>1)&3), byte-in-chunk (q&1)*8.
    int aoff[2][4], boff[2][4];           // [ks][mi/ni]
    #pragma unroll
    for (int ks = 0; ks < 2; ks++)
        #pragma unroll
        for (int m = 0; m < 4; m++) {
            const int ra = wr * 64 + m * 16 + l15;
            const int rb = wc * 64 + m * 16 + l15;
            const int ch = ks * 2 + (quad >> 1);
            const int bo = (quad & 1) * 8;
            aoff[ks][m] = ra * 64 + (ch ^ ((ra >> 1) & 3)) * 16 + bo;
            boff[ks][m] = rb * 64 + (ch ^ ((rb >> 1) & 3)) * 16 + bo;
        }

    f32x4 acc[4][4];
    #pragma unroll
    for (int mi = 0; mi < 4; mi++)
        #pragma unroll
        for (int ni = 0; ni < 4; ni++)
            acc[mi][ni] = (f32x4){0.f, 0.f, 0.f, 0.f};

    for (int kb = 0; kb < D_DIM; kb += BKB) {   // 16 iters
        __syncthreads();   // prev iter's ds_reads done before overwrite
        load_lds16(gA0 + kb, Asmem + seg0 * 1024);
        load_lds16(gA1 + kb, Asmem + seg1 * 1024);
        load_lds16(gB0 + kb, Bsmem + seg0 * 1024);
        load_lds16(gB1 + kb, Bsmem + seg1 * 1024);
        __syncthreads();   // drains vmcnt (compiler-inserted waitcnt)

        #pragma unroll
        for (int ks = 0; ks < 2; ks++) {
            long af[4], bf[4];
            #pragma unroll
            for (int m = 0; m < 4; m++) {
                af[m] = *(const long*)(Asmem + aoff[ks][m]);
                bf[m] = *(const long*)(Bsmem + boff[ks][m]);
            }
            #pragma unroll
            for (int mi = 0; mi < 4; mi++)
                #pragma unroll
                for (int ni = 0; ni < 4; ni++)
                    acc[mi][ni] = __builtin_amdgcn_mfma_f32_16x16x32_fp8_fp8(
                        af[mi], bf[ni], acc[mi][ni], 0, 0, 0);
        }
    }

    // Epilogue. C layout: col = lane&15, row = quad*4 + reg (dtype-indep).
    // sim was computed on 16x-scaled fp8 -> exp factor 2/256.
    float csum[4] = {0.f, 0.f, 0.f, 0.f};
    #pragma unroll
    for (int mi = 0; mi < 4; mi++) {
        const int rowA = rowBase + wr * 64 + mi * 16 + quad * 4;
        float prow[4] = {0.f, 0.f, 0.f, 0.f};
        #pragma unroll
        for (int ni = 0; ni < 4; ni++) {
            const int col = colBase + wc * 64 + ni * 16 + l15;
            const f32x4 a = acc[mi][ni];
            #pragma unroll
            for (int r = 0; r < 4; r++) {
                float e = __expf(a[r] * EXP_SCALE);
                if (isDiag && rowA + r == col) e = 0.0f;   // self-sim mask
                csum[ni] += e;
                prow[r]  += e;
            }
        }
        if (!isDiag) {
            #pragma unroll
            for (int r = 0; r < 4; r++) {   // row sums -> mirror tile
                float v = prow[r];
                v += __shfl_xor(v, 1);
                v += __shfl_xor(v, 2);
                v += __shfl_xor(v, 4);
                v += __shfl_xor(v, 8);
                if (l15 == 0) atomicAdd(denom + rowA + r, v);
            }
        }
    }
    #pragma unroll
    for (int ni = 0; ni < 4; ni++) {        // column sums across 4 quads
        float v = csum[ni];
        v += __shfl_xor(v, 16);
        v += __shfl_xor(v, 32);
        if (quad == 0)
            atomicAdd(denom + colBase + wc * 64 + ni * 16 + l15, v);
    }
}

// ---------------------------------------------------------------------------
// Kernel 3: loss = mean over 2B rows of (log(denom) - pos/T). Single block.
// ---------------------------------------------------------------------------
__global__ __launch_bounds__(256)
void loss_kernel(const float* __restrict__ denom,
                 const float* __restrict__ pos,
                 float* __restrict__ out) {
    const int t = threadIdx.x;
    float s = 0.f;
    for (int i = t; i < N_ROWS; i += 256) {
        const float p = pos[i & (B_ROWS - 1)];
        s += logf(denom[i]) - p * 2.0f;     // TEMP_INV, pos is unscaled fp32
    }
    #pragma unroll
    for (int off = 32; off >= 1; off >>= 1) s += __shfl_xor(s, off);
    __shared__ float red[4];
    if ((t & 63) == 0) red[t >> 6] = s;
    __syncthreads();
    if (t == 0) out[0] = (red[0] + red[1] + red[2] + red[3]) / (float)N_ROWS;
}

// ---------------------------------------------------------------------------
extern "C" void kernel_launch(void* const* d_in, const int* in_sizes, int n_in,
                              void* d_out, int out_size, void* d_ws, size_t ws_size,
                              hipStream_t stream) {
    const float* emb_i = (const float*)d_in[0];
    const float* emb_j = (const float*)d_in[1];

    unsigned char* reps = (unsigned char*)d_ws;                       // 8 MB fp8 [8192][1024]
    float* pos   = (float*)((char*)d_ws + (size_t)N_ROWS * D_DIM);    // 16 KB
    float* denom = pos + B_ROWS;                                      // 32 KB
    float* out   = (float*)d_out;

    normalize_kernel<<<B_ROWS / 4, 256, 0, stream>>>(emb_i, emb_j, reps, pos, denom);
    sim_denom_kernel<<<GRID_SIM, 256, 0, stream>>>(reps, denom);
    loss_kernel<<<1, 256, 0, stream>>>(denom, pos, out);
}

// Round 9
// 136.787 us; speedup vs baseline: 2.9250x; 1.0969x over previous
//
#include <hip/hip_runtime.h>
#include <hip/hip_bf16.h>

// Problem constants (B=4096, D=1024 per reference setup_inputs)
#define B_ROWS 4096
#define D_DIM  1024          // elements == bytes in fp8
#define N_ROWS 8192          // 2B
// values scaled by 16 before fp8 cast -> sim scaled by 256; exp arg factor:
#define EXP_SCALE 0.0078125f // TEMP_INV / 256 = 2/256
#define FP8_SCALE 16.0f

#define NTILE 64
#define GRID_SIM 2080        // upper-triangle tiles incl. diagonal

typedef __attribute__((ext_vector_type(4))) float f32x4;   // MFMA C/D frag
typedef __attribute__((ext_vector_type(8))) int   i32x8;   // MX MFMA A/B frag

// Async global->LDS DMA, 16 B per lane. LDS dest is WAVE-UNIFORM base;
// lane i's 16 B land at base + i*16 (per-lane global addr is free-form).
__device__ inline void load_lds16(const unsigned char* g, unsigned char* l) {
    __builtin_amdgcn_global_load_lds(
        (const __attribute__((address_space(1))) unsigned int*)g,
        (__attribute__((address_space(3))) unsigned int*)l,
        16, 0, 0);
}

// ---------------------------------------------------------------------------
// Kernel 1: wave-per-row L2 normalize -> fp8 e4m3 reps (x16 scale), [8192]
// rows x 1024 B. pos[b] = z_i(b).z_j(b) in fp32 (exact). Zeroes denom.
// ---------------------------------------------------------------------------
__global__ __launch_bounds__(256)
void normalize_kernel(const float* __restrict__ emb_i,
                      const float* __restrict__ emb_j,
                      unsigned char* __restrict__ reps,
                      float* __restrict__ pos,
                      float* __restrict__ denom) {
    const int t    = threadIdx.x;
    const int lane = t & 63;
    const int wave = t >> 6;
    const int b    = blockIdx.x * 4 + wave;          // 0..4095

    if (blockIdx.x < N_ROWS / 256) denom[blockIdx.x * 256 + t] = 0.0f;

    const float4* pi = (const float4*)(emb_i + (size_t)b * D_DIM) + lane * 4;
    const float4* pj = (const float4*)(emb_j + (size_t)b * D_DIM) + lane * 4;

    float4 vi[4], vj[4];
    float si = 0.f, sj = 0.f, sd = 0.f;
    #pragma unroll
    for (int k = 0; k < 4; k++) {
        vi[k] = pi[k]; vj[k] = pj[k];
        si += vi[k].x*vi[k].x + vi[k].y*vi[k].y + vi[k].z*vi[k].z + vi[k].w*vi[k].w;
        sj += vj[k].x*vj[k].x + vj[k].y*vj[k].y + vj[k].z*vj[k].z + vj[k].w*vj[k].w;
        sd += vi[k].x*vj[k].x + vi[k].y*vj[k].y + vi[k].z*vj[k].z + vi[k].w*vj[k].w;
    }
    #pragma unroll
    for (int off = 32; off >= 1; off >>= 1) {   // butterfly: all lanes get sums
        si += __shfl_xor(si, off);
        sj += __shfl_xor(sj, off);
        sd += __shfl_xor(sd, off);
    }
    const float inv_i = FP8_SCALE / fmaxf(sqrtf(si), 1e-12f);
    const float inv_j = FP8_SCALE / fmaxf(sqrtf(sj), 1e-12f);
    if (lane == 0) pos[b] = sd * (inv_i * inv_j) * (1.0f / (FP8_SCALE * FP8_SCALE));

    uint4 wi, wj;
    unsigned int* wip = (unsigned int*)&wi;
    unsigned int* wjp = (unsigned int*)&wj;
    #pragma unroll
    for (int k = 0; k < 4; k++) {
        int a = __builtin_amdgcn_cvt_pk_fp8_f32(vi[k].x * inv_i, vi[k].y * inv_i, 0, false);
        wip[k] = __builtin_amdgcn_cvt_pk_fp8_f32(vi[k].z * inv_i, vi[k].w * inv_i, a, true);
        int c = __builtin_amdgcn_cvt_pk_fp8_f32(vj[k].x * inv_j, vj[k].y * inv_j, 0, false);
        wjp[k] = __builtin_amdgcn_cvt_pk_fp8_f32(vj[k].z * inv_j, vj[k].w * inv_j, c, true);
    }
    *(uint4*)(reps + (size_t)b * D_DIM + lane * 16)            = wi;
    *(uint4*)(reps + (size_t)(b + B_ROWS) * D_DIM + lane * 16) = wj;
}

// ---------------------------------------------------------------------------
// Kernel 2: symmetry-halved fused sim -> exp -> denom, MX-scaled fp8 MFMA
// (mfma_scale_f32_16x16x128_f8f6f4, unit e8m0 scales = plain fp8 matmul at
// 2x the non-scaled rate — m148 ladder step). One 128x128 upper-triangle
// tile per block (grid 2080, R7 balanced grouped enumeration).
// BKB = 128 B: 8 K-iters (half of R8 — half the barriers), MFMA pipe-time
// halves. LDS: 128-B rows; 16-B chunk c of row r at slot c ^ (r&7).
// Fragment reads: per m-frag two ds_read_b128 at off, off^16 — 64 lanes
// spread 8-per-4-bank-group, the same uniformity class as R7's measured
// 0-conflict pattern (R8's b64 pattern was non-uniform: 8.5e6 conflicts).
// A and B use the same lane->k map, so the k-permutation cancels in the dot
// product; C/D layout is shape-determined (col=lane&15, row=quad*4+reg).
// ---------------------------------------------------------------------------
#define BM 128
#define BKB 128              // K-bytes (== elements) staged per iter

__global__ __launch_bounds__(256, 3)
void sim_denom_kernel(const unsigned char* __restrict__ reps,
                      float* __restrict__ denom) {
    // ---- tile decode: bid -> (rt, ct), rt <= ct (R7 grouped enumeration) ----
    const int bid = blockIdx.x;
    int g = (int)((__builtin_sqrtf(1.0f + 8.0f * (float)bid) - 1.0f) * 0.125f);
    while (8 * (g + 1) * (g + 1) + 2 * (g + 1) <= bid) g++;
    while (8 * g * g + 2 * g > bid) g--;
    const int i = bid - (8 * g * g + 2 * g);    // [0, 16g+10)
    int rt, c;
    if (i < 16 * g + 4) { rt = i >> 2; c = i & 3; }
    else {
        const int r2 = i - (16 * g + 4);        // 0..5
        const int ra[6] = {1, 1, 1, 2, 2, 3};
        const int ca[6] = {1, 2, 3, 2, 3, 3};
        rt = 4 * g + ra[r2]; c = ca[r2];
    }
    const int ct = 4 * g + c;
    const bool isDiag = (rt == ct);
    const int rowBase = rt * BM;
    const int colBase = ct * BM;

    const int t    = threadIdx.x;
    const int lane = t & 63;
    const int wave = t >> 6;
    const int wr   = wave >> 1;           // wave row quadrant (0/1)
    const int wc   = wave & 1;            // wave col quadrant (0/1)
    const int quad = lane >> 4;           // 0..3
    const int l15  = lane & 15;

    __shared__ __align__(16) unsigned char Asmem[BM * BKB];   // 16 KB
    __shared__ __align__(16) unsigned char Bsmem[BM * BKB];   // 16 KB

    // staging lane map: per call a wave stages 8 rows (1 KB). lane i ->
    // row (i>>3) within the 8-row segment, LDS slot i&7; global chunk
    // (i&7)^((i>>3)&7) so that stored slot == chunk ^ (row&7).
    const int grow = lane >> 3;                              // 0..7
    const int gcol = ((lane & 7) ^ grow) * 16;               // swizzled chunk
    const unsigned char* gA = reps + (size_t)(rowBase + wave * 8 + grow) * D_DIM + gcol;
    const unsigned char* gB = reps + (size_t)(colBase + wave * 8 + grow) * D_DIM + gcol;
    unsigned char* lA = Asmem + wave * 8 * BKB;              // call j adds j*32*BKB
    unsigned char* lB = Bsmem + wave * 8 * BKB;

    // fragment read offsets: m-frag row ra = wr*64 + m*16 + l15; lane reads
    // logical chunks {2*quad, 2*quad+1} (k = quad*32..+32) at slots
    // chunk^(ra&7) -> base off + (off^16).
    int aoff[4], boff[4];
    #pragma unroll
    for (int m = 0; m < 4; m++) {
        const int ra = wr * 64 + m * 16 + l15;
        const int rb = wc * 64 + m * 16 + l15;
        aoff[m] = ra * BKB + ((2 * quad) ^ (ra & 7)) * 16;
        boff[m] = rb * BKB + ((2 * quad) ^ (rb & 7)) * 16;
    }

    f32x4 acc[4][4];
    #pragma unroll
    for (int mi = 0; mi < 4; mi++)
        #pragma unroll
        for (int ni = 0; ni < 4; ni++)
            acc[mi][ni] = (f32x4){0.f, 0.f, 0.f, 0.f};

    for (int kb = 0; kb < D_DIM; kb += BKB) {   // 8 iters
        __syncthreads();   // prev iter's ds_reads done before overwrite
        #pragma unroll
        for (int j = 0; j < 4; j++) {           // 4 calls x 32 rows each tile
            load_lds16(gA + kb + j * 32 * D_DIM, lA + j * 32 * BKB);
            load_lds16(gB + kb + j * 32 * D_DIM, lB + j * 32 * BKB);
        }
        __syncthreads();   // drains vmcnt (compiler-inserted waitcnt)

        i32x8 af[4], bf[4];
        #pragma unroll
        for (int m = 0; m < 4; m++) {
            const int4 alo = *(const int4*)(Asmem + aoff[m]);
            const int4 ahi = *(const int4*)(Asmem + (aoff[m] ^ 16));
            af[m] = (i32x8){alo.x, alo.y, alo.z, alo.w, ahi.x, ahi.y, ahi.z, ahi.w};
            const int4 blo = *(const int4*)(Bsmem + boff[m]);
            const int4 bhi = *(const int4*)(Bsmem + (boff[m] ^ 16));
            bf[m] = (i32x8){blo.x, blo.y, blo.z, blo.w, bhi.x, bhi.y, bhi.z, bhi.w};
        }

        #pragma unroll
        for (int mi = 0; mi < 4; mi++)
            #pragma unroll
            for (int ni = 0; ni < 4; ni++)
                acc[mi][ni] = __builtin_amdgcn_mfma_scale_f32_16x16x128_f8f6f4(
                    af[mi], bf[ni], acc[mi][ni],
                    0, 0,          // cbsz=0 (fp8 e4m3 A), blgp=0 (fp8 e4m3 B)
                    0, 127,        // scale A: opsel 0, e8m0 127 = 1.0
                    0, 127);       // scale B: unit
    }

    // Epilogue. C layout: col = lane&15, row = quad*4 + reg (shape-determined).
    // sim computed on 16x-scaled fp8 -> exp factor 2/256.
    float csum[4] = {0.f, 0.f, 0.f, 0.f};
    #pragma unroll
    for (int mi = 0; mi < 4; mi++) {
        const int rowA = rowBase + wr * 64 + mi * 16 + quad * 4;
        float prow[4] = {0.f, 0.f, 0.f, 0.f};
        #pragma unroll
        for (int ni = 0; ni < 4; ni++) {
            const int col = colBase + wc * 64 + ni * 16 + l15;
            const f32x4 a = acc[mi][ni];
            #pragma unroll
            for (int r = 0; r < 4; r++) {
                float e = __expf(a[r] * EXP_SCALE);
                if (isDiag && rowA + r == col) e = 0.0f;   // self-sim mask
                csum[ni] += e;
                prow[r]  += e;
            }
        }
        if (!isDiag) {
            #pragma unroll
            for (int r = 0; r < 4; r++) {   // row sums -> mirror tile
                float v = prow[r];
                v += __shfl_xor(v, 1);
                v += __shfl_xor(v, 2);
                v += __shfl_xor(v, 4);
                v += __shfl_xor(v, 8);
                if (l15 == 0) atomicAdd(denom + rowA + r, v);
            }
        }
    }
    #pragma unroll
    for (int ni = 0; ni < 4; ni++) {        // column sums across 4 quads
        float v = csum[ni];
        v += __shfl_xor(v, 16);
        v += __shfl_xor(v, 32);
        if (quad == 0)
            atomicAdd(denom + colBase + wc * 64 + ni * 16 + l15, v);
    }
}

// ---------------------------------------------------------------------------
// Kernel 3: loss = mean over 2B rows of (log(denom) - pos/T). Single block.
// ---------------------------------------------------------------------------
__global__ __launch_bounds__(256)
void loss_kernel(const float* __restrict__ denom,
                 const float* __restrict__ pos,
                 float* __restrict__ out) {
    const int t = threadIdx.x;
    float s = 0.f;
    for (int i = t; i < N_ROWS; i += 256) {
        const float p = pos[i & (B_ROWS - 1)];
        s += logf(denom[i]) - p * 2.0f;     // TEMP_INV, pos is unscaled fp32
    }
    #pragma unroll
    for (int off = 32; off >= 1; off >>= 1) s += __shfl_xor(s, off);
    __shared__ float red[4];
    if ((t & 63) == 0) red[t >> 6] = s;
    __syncthreads();
    if (t == 0) out[0] = (red[0] + red[1] + red[2] + red[3]) / (float)N_ROWS;
}

// ---------------------------------------------------------------------------
extern "C" void kernel_launch(void* const* d_in, const int* in_sizes, int n_in,
                              void* d_out, int out_size, void* d_ws, size_t ws_size,
                              hipStream_t stream) {
    const float* emb_i = (const float*)d_in[0];
    const float* emb_j = (const float*)d_in[1];

    unsigned char* reps = (unsigned char*)d_ws;                       // 8 MB fp8 [8192][1024]
    float* pos   = (float*)((char*)d_ws + (size_t)N_ROWS * D_DIM);    // 16 KB
    float* denom = pos + B_ROWS;                                      // 32 KB
    float* out   = (float*)d_out;

    normalize_kernel<<<B_ROWS / 4, 256, 0, stream>>>(emb_i, emb_j, reps, pos, denom);
    sim_denom_kernel<<<GRID_SIM, 256, 0, stream>>>(reps, denom);
    loss_kernel<<<1, 256, 0, stream>>>(denom, pos, out);
}